// Round 11
// baseline (784.503 us; speedup 1.0000x reference)
//
#include <hip/hip_runtime.h>

// SimpleLSTM: 2-layer LSTM (B=512,T=256,F=64,U=128) + Dense(1,relu).
// R11: in-WG fused layers, SPLIT BY WAVE (fixes R10's VGPR blowup: every
// wave held uf1+uf2=128 regs + dual accs -> demotion -> reload storms).
// Waves 0-3 = layer1 (32 units each, uf1 resident), waves 4-7 = layer2.
// L2 lags L1 by 8 steps; h1 via 16-slot LDS ring; h2 via LDS dbuf.
// xz (time-batched M=16 x@W / h1@W2, 8 steps/block) is WAVE-LOCAL: each
// wave computes+consumes xz for its own 32 units -> no xz sync at all.
// One LDS-only barrier/step (h1/h2 cross-wave). hs never hits global.
// 256 WGs x 512 thr, 2 batch rows/WG, 264 steps total.

#define T_STEPS 256
#define BATCH   512
#define NU      128
#define FDIM    64
#define PH      136   // h row pitch (halfs); 272 B, 16B-aligned

typedef _Float16 h8 __attribute__((ext_vector_type(8)));
typedef float    f4 __attribute__((ext_vector_type(4)));

#define LOG2E    1.4426950408889634f
#define TWOLOG2E 2.8853900817779268f

// LDS-only barrier: cross-step deps are LDS; no global stores in loop.
#define WG_BARRIER() asm volatile("s_waitcnt lgkmcnt(0)\n\ts_barrier" ::: "memory")

#if __has_builtin(__builtin_amdgcn_exp2f)
#define EXP2F(x) __builtin_amdgcn_exp2f(x)
#else
#define EXP2F(x) exp2f(x)
#endif
#if __has_builtin(__builtin_amdgcn_rcpf)
#define RCPF(x) __builtin_amdgcn_rcpf(x)
#else
#define RCPF(x) (1.0f / (x))
#endif

__device__ __forceinline__ float sigm2(float s) {   // s = -z*log2e
    return RCPF(1.0f + EXP2F(s));
}
__device__ __forceinline__ float tanh2(float t) {   // t = 2*z*log2e
    return 1.0f - 2.0f * RCPF(1.0f + EXP2F(t));
}

// ---- weight prep: col-major [col][k], fp16, gate-folded log2e signs ----
// gates 0=i 1=f 2=g 3=o; i/f/o scaled -log2e (sigm2), g scaled +2log2e.
__global__ void prep_weights(const float* __restrict__ W1, const float* __restrict__ U1,
                             const float* __restrict__ b1, const float* __restrict__ W2,
                             const float* __restrict__ U2, const float* __restrict__ b2,
                             _Float16* __restrict__ Wp1, _Float16* __restrict__ Up1,
                             _Float16* __restrict__ Wp2, _Float16* __restrict__ Up2,
                             float* __restrict__ bp1, float* __restrict__ bp2) {
    int i = blockIdx.x * 256 + threadIdx.x;
    if (i < 32768) {                        // Wp1 [512][64] <- W1 [64][512]
        int col = i >> 6, k = i & 63;
        float sc = ((col >> 7) == 2) ? TWOLOG2E : -LOG2E;
        Wp1[i] = (_Float16)(W1[k * 512 + col] * sc);
    } else if (i < 98304) {                 // Up1 [512][128] <- U1
        int j = i - 32768; int col = j >> 7, k = j & 127;
        float sc = ((col >> 7) == 2) ? TWOLOG2E : -LOG2E;
        Up1[j] = (_Float16)(U1[k * 512 + col] * sc);
    } else if (i < 163840) {                // Wp2 [512][128] <- W2
        int j = i - 98304; int col = j >> 7, k = j & 127;
        float sc = ((col >> 7) == 2) ? TWOLOG2E : -LOG2E;
        Wp2[j] = (_Float16)(W2[k * 512 + col] * sc);
    } else if (i < 229376) {                // Up2 [512][128] <- U2
        int j = i - 163840; int col = j >> 7, k = j & 127;
        float sc = ((col >> 7) == 2) ? TWOLOG2E : -LOG2E;
        Up2[j] = (_Float16)(U2[k * 512 + col] * sc);
    } else if (i < 230400) {
        int j = i - 229376;
        if (j < 512) {
            float sc = ((j >> 7) == 2) ? TWOLOG2E : -LOG2E;
            bp1[j] = b1[j] * sc;
        } else {
            int col = j - 512;
            float sc = ((col >> 7) == 2) ? TWOLOG2E : -LOG2E;
            bp2[col] = b2[col] * sc;
        }
    }
}

__attribute__((amdgpu_waves_per_eu(2, 2)))
__global__ __launch_bounds__(512) void lstm_fused(
    const float* __restrict__ x,
    const _Float16* __restrict__ Wp1, const _Float16* __restrict__ Up1,
    const float* __restrict__ bp1,
    const _Float16* __restrict__ Wp2, const _Float16* __restrict__ Up2,
    const float* __restrict__ bp2,
    const float* __restrict__ Wd, const float* __restrict__ bd,
    float* __restrict__ dout) {
    // h1 ring: [16 slot][2 row][PH]; h2 dbuf: [2 par][2 row][PH]
    __shared__ __align__(16) _Float16 smh[36 * PH];
    // xz: [layer(2)][half(2)][r16=s*2+row (16)][u 128][g 4] f32 = 128 KB
    __shared__ __align__(16) float smxz[32768];
    _Float16* h1r = smh;
    _Float16* h2r = smh + 32 * PH;

    const int tid  = threadIdx.x;
    const int lane = tid & 63;
    const int wv   = tid >> 6;
    const int m    = lane & 15;
    const int kc   = lane >> 4;
    const bool isL1 = (wv < 4);
    const int wu   = (wv & 3) * 32;      // this wave's 32-unit base
    const int b0   = blockIdx.x * 2;

    float* xzme = smxz + (isL1 ? 0 : 16384);   // wave-local xz region

    for (int i = tid; i < 36 * PH; i += 512) smh[i] = (_Float16)0.0f;

    const _Float16* Up = isL1 ? Up1 : Up2;
    const _Float16* Wp = isL1 ? Wp1 : Wp2;
    const float*   bpp = isL1 ? bp1 : bp2;

    // resident recurrent B-frags: 2 N-tiles x 4 gates x K128 = 32 h8 = 128 VGPR
    h8 uf[2][4][4];
#pragma unroll
    for (int nt = 0; nt < 2; nt++)
#pragma unroll
        for (int g = 0; g < 4; g++)
#pragma unroll
            for (int ks = 0; ks < 4; ks++)
                uf[nt][g][ks] = *(const h8*)&Up[(g * 128 + wu + nt * 16 + m) * 128
                                                + ks * 32 + kc * 8];
    float bias[2][4];
#pragma unroll
    for (int nt = 0; nt < 2; nt++)
#pragma unroll
        for (int g = 0; g < 4; g++)
            bias[nt][g] = bpp[g * 128 + wu + nt * 16 + m];

    // ---- x-block machinery (A rows: r16 = s*2 + brow; lane m -> row m) ----
    f4 rX[2][2];                          // L1 x prefetch regs
    auto loadX = [&](int blk) {           // L1 only
        const int tt = blk * 8 + (m >> 1), bb = b0 + (m & 1);
        const float* xp = &x[((size_t)bb * T_STEPS + tt) * FDIM];
        rX[0][0] = *(const f4*)&xp[kc * 8];
        rX[0][1] = *(const f4*)&xp[kc * 8 + 4];
        rX[1][0] = *(const f4*)&xp[32 + kc * 8];
        rX[1][1] = *(const f4*)&xp[32 + kc * 8 + 4];
    };
    auto calcX1 = [&](int blk) {          // x @ W1 for this wave's 32 units
        h8 a[2];
#pragma unroll
        for (int ks = 0; ks < 2; ks++) {
            f4 lo = rX[ks][0], hi = rX[ks][1];
#pragma unroll
            for (int j = 0; j < 4; j++) { a[ks][j] = (_Float16)lo[j]; a[ks][4 + j] = (_Float16)hi[j]; }
        }
        float* dst = &xzme[(blk & 1) * 8192];
#pragma unroll
        for (int nt = 0; nt < 2; nt++) {
            f4 ax[4];
#pragma unroll
            for (int g = 0; g < 4; g++) ax[g] = (f4){bias[nt][g], bias[nt][g], bias[nt][g], bias[nt][g]};
#pragma unroll
            for (int ks = 0; ks < 2; ks++)
#pragma unroll
                for (int g = 0; g < 4; g++) {
                    h8 w = *(const h8*)&Wp[(g * 128 + wu + nt * 16 + m) * 64 + ks * 32 + kc * 8];
                    ax[g] = __builtin_amdgcn_mfma_f32_16x16x32_f16(a[ks], w, ax[g], 0, 0, 0);
                }
#pragma unroll
            for (int rr = 0; rr < 4; rr++) {
                f4 v = {ax[0][rr], ax[1][rr], ax[2][rr], ax[3][rr]};
                *(f4*)&dst[((kc * 4 + rr) * 128 + wu + nt * 16 + m) * 4] = v;
            }
        }
    };
    auto calcX2 = [&](int blk) {          // h1-ring @ W2 for this wave's 32 units
        const int slot = ((blk & 1) * 8 + (m >> 1));
        const _Float16* hp = &h1r[(slot * 2 + (m & 1)) * PH];
        h8 a[4];
#pragma unroll
        for (int ks = 0; ks < 4; ks++) a[ks] = *(const h8*)&hp[ks * 32 + kc * 8];
        float* dst = &xzme[(blk & 1) * 8192];
#pragma unroll
        for (int nt = 0; nt < 2; nt++) {
            f4 ax[4];
#pragma unroll
            for (int g = 0; g < 4; g++) ax[g] = (f4){bias[nt][g], bias[nt][g], bias[nt][g], bias[nt][g]};
#pragma unroll
            for (int ks = 0; ks < 4; ks++)
#pragma unroll
                for (int g = 0; g < 4; g++) {
                    h8 w = *(const h8*)&Wp[(g * 128 + wu + nt * 16 + m) * 128 + ks * 32 + kc * 8];
                    ax[g] = __builtin_amdgcn_mfma_f32_16x16x32_f16(a[ks], w, ax[g], 0, 0, 0);
                }
#pragma unroll
            for (int rr = 0; rr < 4; rr++) {
                f4 v = {ax[0][rr], ax[1][rr], ax[2][rr], ax[3][rr]};
                *(f4*)&dst[((kc * 4 + rr) * 128 + wu + nt * 16 + m) * 4] = v;
            }
        }
    };

    __syncthreads();                      // zeroed h visible

    if (isL1) { loadX(0); calcX1(0); loadX(1); }   // xz1 block0 ready (wave-local)

    const h8 hz = {};
    h8 ha[4];
#pragma unroll
    for (int ks = 0; ks < 4; ks++) ha[ks] = hz;
    f4 fz = (f4){0.f, 0.f, 0.f, 0.f};
    asm volatile("" : "+v"(fz));
    float cst[2] = {0.0f, 0.0f};          // 2 chains/lane (nt=0,1), lanes<32

    for (int b = 0; b < 33; b++) {
#pragma unroll
        for (int s = 0; s < 8; s++) {
            const int t   = b * 8 + s;
            const bool act = isL1 ? (b < 32) : (b >= 1);
            const int tau = t - (isL1 ? 0 : 8);
            const int rhalf = isL1 ? (b & 1) : ((b - 1) & 1);  // xz half to read

            // A-frag ds_reads first (dep: prev step's h, post-barrier)
            if (act && ((m & 3) == 0) && (m < 8)) {
                const _Float16* src = isL1
                    ? &h1r[(((t - 1) & 15) * 2 + (m >> 2)) * PH]
                    : &h2r[((tau & 1) * 2 + (m >> 2)) * PH];
#pragma unroll
                for (int ks = 0; ks < 4; ks++)
                    ha[ks] = *(const h8*)&src[ks * 32 + kc * 8];
            }

            // block-boundary xz work (fills ha-latency window; wave-local)
            if (s == 0) {
                if (isL1) { if (b + 1 < 32) calcX1(b + 1); }
                else      { if (b >= 1)     calcX2(b - 1); }
            }
            if (s == 1 && isL1 && b + 2 < 32) loadX(b + 2);

            // h @ U : 32 MFMAs (2 N-tiles x 4 gates x K128)
            f4 acc[2][4];
            if (act) {
#pragma unroll
                for (int nt = 0; nt < 2; nt++)
#pragma unroll
                    for (int g = 0; g < 4; g++)
                        acc[nt][g] = __builtin_amdgcn_mfma_f32_16x16x32_f16(ha[0], uf[nt][g][0], fz, 0, 0, 0);
#pragma unroll
                for (int ks = 1; ks < 4; ks++)
#pragma unroll
                    for (int nt = 0; nt < 2; nt++)
#pragma unroll
                        for (int g = 0; g < 4; g++)
                            acc[nt][g] = __builtin_amdgcn_mfma_f32_16x16x32_f16(ha[ks], uf[nt][g][ks], acc[nt][g], 0, 0, 0);
            }

            // epilogue: lanes 0..31, rows 0/1 in reg0; 2 unit-chains per lane
            if (act && lane < 32) {
                const int row = lane >> 4;
#pragma unroll
                for (int nt = 0; nt < 2; nt++) {
                    const f4 xzv = *(const f4*)&xzme[rhalf * 8192
                                        + ((s * 2 + row) * 128 + wu + nt * 16 + (lane & 15)) * 4];
                    float gi = sigm2(acc[nt][0][0] + xzv[0]);
                    float gf = sigm2(acc[nt][1][0] + xzv[1]);
                    float gg = tanh2(acc[nt][2][0] + xzv[2]);
                    float go = sigm2(acc[nt][3][0] + xzv[3]);
                    cst[nt] = gf * cst[nt] + gi * gg;
                    float hv = go * tanh2(cst[nt] * TWOLOG2E);
                    _Float16 h16 = (_Float16)hv;
                    _Float16* dst = isL1
                        ? &h1r[((t & 15) * 2 + row) * PH + wu + nt * 16 + (lane & 15)]
                        : &h2r[(((tau & 1) ^ 1) * 2 + row) * PH + wu + nt * 16 + (lane & 15)];
                    *dst = h16;
                }
            }
            WG_BARRIER();
        }
    }

    // dense: final h2 (tau=255) in parity 0
    if (wv == 0 && lane < 32) {
        const int rw = lane >> 4, u = lane & 15;
        const _Float16* hb = &h2r[rw * PH];
        float sa = 0.0f;
#pragma unroll
        for (int j = 0; j < 8; j++)
            sa += (float)hb[u + 16 * j] * Wd[u + 16 * j];
        sa += __shfl_xor(sa, 1);
        sa += __shfl_xor(sa, 2);
        sa += __shfl_xor(sa, 4);
        sa += __shfl_xor(sa, 8);
        if (u == 0) dout[b0 + rw] = fmaxf(sa + bd[0], 0.0f);
    }
}

extern "C" void kernel_launch(void* const* d_in, const int* in_sizes, int n_in,
                              void* d_out, int out_size, void* d_ws, size_t ws_size,
                              hipStream_t stream) {
    const float* x  = (const float*)d_in[0];
    const float* W1 = (const float*)d_in[1];
    const float* U1 = (const float*)d_in[2];
    const float* b1 = (const float*)d_in[3];
    const float* W2 = (const float*)d_in[4];
    const float* U2 = (const float*)d_in[5];
    const float* b2 = (const float*)d_in[6];
    const float* Wd = (const float*)d_in[7];
    const float* bd = (const float*)d_in[8];
    float* out = (float*)d_out;

    const size_t oWp1 = 0;                 // 65536 B
    const size_t oUp1 = 65536;             // 131072 B
    const size_t oWp2 = 196608;            // 131072 B
    const size_t oUp2 = 327680;            // 131072 B
    const size_t oBp1 = 458752;            // 2048 B
    const size_t oBp2 = 460800;            // 2048 B
    const size_t need = 462848;
    if (ws_size < need) return;

    char* ws = (char*)d_ws;
    _Float16* Wp1 = (_Float16*)(ws + oWp1);
    _Float16* Up1 = (_Float16*)(ws + oUp1);
    _Float16* Wp2 = (_Float16*)(ws + oWp2);
    _Float16* Up2 = (_Float16*)(ws + oUp2);
    float*    bp1 = (float*)(ws + oBp1);
    float*    bp2 = (float*)(ws + oBp2);

    prep_weights<<<900, 256, 0, stream>>>(W1, U1, b1, W2, U2, b2,
                                          Wp1, Up1, Wp2, Up2, bp1, bp2);
    lstm_fused<<<256, 512, 0, stream>>>(x, Wp1, Up1, bp1, Wp2, Up2, bp2,
                                        Wd, bd, out);
}